// Round 1
// baseline (111.987 us; speedup 1.0000x reference)
//
#include <hip/hip_runtime.h>

#define MAX_SEQ   2048
#define LAT_SEQ   1024
#define DIM       1024
#define DLAT      5
#define K_CB      4375
#define ZERO_IDX  2187   // (0+3)*625 + (0+2)*125 + (0+2)*25 + (0+2)*5 + (0+2)

// ---------------------------------------------------------------------------
// K0: zero the usage bitmap; the all-zero code is always used (masked tokens).
__global__ void init_used(int* __restrict__ used) {
    int i = blockIdx.x * blockDim.x + threadIdx.x;
    if (i < K_CB) used[i] = (i == ZERO_IDX) ? 1 : 0;
}

// ---------------------------------------------------------------------------
// K1: fused encode -> FSQ quantize -> usage mark -> decode, one wave per token.
__global__ __launch_bounds__(256) void fsq_fused(
    const float* __restrict__ x,
    const float* __restrict__ Wenc,   // [1024][5]
    const float* __restrict__ Wdec,   // [5][1024]
    float* __restrict__ xout,         // [32768][1024]
    float* __restrict__ ze,           // [32768][5]
    float* __restrict__ zq,           // [32768][5]
    int*   __restrict__ used)         // [4375]
{
    const int wave = threadIdx.x >> 6;
    const int lane = threadIdx.x & 63;
    const int t    = blockIdx.x * 4 + wave;          // token id, grid covers 32768
    const int s    = t & (MAX_SEQ - 1);              // position within sequence
    const int col  = lane * 16;                      // 16 contiguous columns per lane
    const long long base = (long long)t * DIM + col;
    float4* outp = (float4*)(xout + base);

    if (s >= LAT_SEQ) {
        // masked token: z = 0 everywhere, x_out row = 0. No loads needed.
        const float4 z4 = make_float4(0.f, 0.f, 0.f, 0.f);
        outp[0] = z4; outp[1] = z4; outp[2] = z4; outp[3] = z4;
        if (lane < DLAT) {
            ze[t * DLAT + lane] = 0.f;
            zq[t * DLAT + lane] = 0.f;
        }
        return;
    }

    // ---- encode: h[e] = sum_d x[t,d] * Wenc[d,e]
    const float4* xp = (const float4*)(x + base);
    float acc[DLAT] = {0.f, 0.f, 0.f, 0.f, 0.f};
    #pragma unroll
    for (int q = 0; q < 4; ++q) {
        const float4 v = xp[q];
        const float vv[4] = {v.x, v.y, v.z, v.w};
        #pragma unroll
        for (int j = 0; j < 4; ++j) {
            const float* w = Wenc + (size_t)(col + q * 4 + j) * DLAT;
            #pragma unroll
            for (int e = 0; e < DLAT; ++e) acc[e] += vv[j] * w[e];
        }
    }
    // butterfly reduce across the 64-lane wave (all lanes end with the full sum)
    #pragma unroll
    for (int e = 0; e < DLAT; ++e) {
        float a = acc[e];
        #pragma unroll
        for (int o = 32; o > 0; o >>= 1) a += __shfl_xor(a, o, 64);
        acc[e] = a;
    }

    // ---- FSQ quantize: z_q = rint(half * tanh(h))   (rint = half-to-even, like jnp.round)
    const float halfv[DLAT] = {3.f, 2.f, 2.f, 2.f, 2.f};
    float zqv[DLAT];
    int   ci[DLAT];
    #pragma unroll
    for (int e = 0; e < DLAT; ++e) {
        const float zsq = halfv[e] * tanhf(acc[e]);
        zqv[e] = rintf(zsq);
        ci[e]  = (int)zqv[e];
    }

    if (lane < DLAT) {
        ze[t * DLAT + lane] = acc[lane];
        zq[t * DLAT + lane] = zqv[lane];
    }
    if (lane == 0) {
        const int idx = ((((ci[0] + 3) * 5 + (ci[1] + 2)) * 5 + (ci[2] + 2)) * 5
                          + (ci[3] + 2)) * 5 + (ci[4] + 2);
        used[idx] = 1;   // benign race: everyone stores 1
    }

    // ---- decode: x_out[t,d] = sum_e z_q[e] * Wdec[e,d]
    #pragma unroll
    for (int q = 0; q < 4; ++q) {
        float4 o;
        float* op = (float*)&o;
        #pragma unroll
        for (int j = 0; j < 4; ++j) {
            const int d = col + q * 4 + j;
            float sum = 0.f;
            #pragma unroll
            for (int e = 0; e < DLAT; ++e) sum += zqv[e] * Wdec[e * DIM + d];
            op[j] = sum;
        }
        outp[q] = o;
    }
}

// ---------------------------------------------------------------------------
// K2: reduce usage flags -> unique; write the three scalar outputs.
__global__ void finalize(const int* __restrict__ used, float* __restrict__ scal) {
    __shared__ int sh[256];
    const int t = threadIdx.x;
    int sum = 0;
    for (int i = t; i < K_CB; i += 256) sum += used[i];
    sh[t] = sum;
    __syncthreads();
    for (int o = 128; o > 0; o >>= 1) {
        if (t < o) sh[t] += sh[t + o];
        __syncthreads();
    }
    if (t == 0) {
        const float uniq  = (float)sh[0];
        const float usage = (uniq + ((float)K_CB - uniq) * expf(-1.0f)) / (float)K_CB;
        scal[0] = usage;          // output 3: usage
        scal[1] = uniq;           // output 4: unique (int32 value, stored as float)
        scal[2] = 0.0f;           // output 5: percent_masked
    }
}

// ---------------------------------------------------------------------------
extern "C" void kernel_launch(void* const* d_in, const int* in_sizes, int n_in,
                              void* d_out, int out_size, void* d_ws, size_t ws_size,
                              hipStream_t stream) {
    const float* x    = (const float*)d_in[0];   // [16,2048,1024]
    const float* Wenc = (const float*)d_in[1];   // [1024,5]
    const float* Wdec = (const float*)d_in[2];   // [5,1024]

    float* out  = (float*)d_out;
    float* xout = out;                                  // 33554432
    float* ze   = out + 33554432;                       // 163840
    float* zq   = ze + 163840;                          // 163840
    float* scal = zq + 163840;                          // 3 scalars

    int* used = (int*)d_ws;                             // 4375 ints

    init_used<<<(K_CB + 255) / 256, 256, 0, stream>>>(used);
    fsq_fused<<<(32768 / 4), 256, 0, stream>>>(x, Wenc, Wdec, xout, ze, zq, used);
    finalize<<<1, 256, 0, stream>>>(used, scal);
}

// Round 2
// 64.380 us; speedup vs baseline: 1.7395x; 1.7395x over previous
//
#include <hip/hip_runtime.h>

#define MAX_SEQ   2048
#define LAT_SEQ   1024
#define DIM       1024
#define DLAT      5
#define K_CB      4375
#define ZERO_IDX  2187   // (0+3)*625 + (0+2)*125 + (0+2)*25 + (0+2)*5 + (0+2)

// ---------------------------------------------------------------------------
// K0: zero the usage bitmap; the all-zero code is always used (masked tokens).
__global__ void init_used(int* __restrict__ used) {
    int i = blockIdx.x * blockDim.x + threadIdx.x;
    if (i < K_CB) used[i] = (i == ZERO_IDX) ? 1 : 0;
}

// ---------------------------------------------------------------------------
// K1: fused encode -> FSQ quantize -> usage mark -> decode, one wave per token.
// Lane-contiguous layout: memory instruction q covers the contiguous 1 KB
// slice [q*256, q*256+256) of the token row; lane i owns float4 at q*256+i*4.
__global__ __launch_bounds__(256) void fsq_fused(
    const float* __restrict__ x,
    const float* __restrict__ Wenc,   // [1024][5]
    const float* __restrict__ Wdec,   // [5][1024]
    float* __restrict__ xout,         // [32768][1024]
    float* __restrict__ ze,           // [32768][5]
    float* __restrict__ zq,           // [32768][5]
    int*   __restrict__ used)         // [4375]
{
    const int wave = threadIdx.x >> 6;
    const int lane = threadIdx.x & 63;
    const int t    = blockIdx.x * 4 + wave;          // token id, grid covers 32768
    const int s    = t & (MAX_SEQ - 1);              // position within sequence
    const long long row = (long long)t * DIM;

    if (s >= LAT_SEQ) {
        // masked token: z = 0 everywhere, x_out row = 0. No loads needed.
        const float4 z4 = make_float4(0.f, 0.f, 0.f, 0.f);
        #pragma unroll
        for (int q = 0; q < 4; ++q)
            *(float4*)(xout + row + q * 256 + lane * 4) = z4;
        if (lane < DLAT) {
            ze[t * DLAT + lane] = 0.f;
            zq[t * DLAT + lane] = 0.f;
        }
        return;
    }

    // ---- encode: h[e] = sum_d x[t,d] * Wenc[d,e]
    float acc[DLAT] = {0.f, 0.f, 0.f, 0.f, 0.f};
    #pragma unroll
    for (int q = 0; q < 4; ++q) {
        const int c0 = q * 256 + lane * 4;
        const float4 v = *(const float4*)(x + row + c0);
        const float vv[4] = {v.x, v.y, v.z, v.w};
        #pragma unroll
        for (int j = 0; j < 4; ++j) {
            const float* w = Wenc + (size_t)(c0 + j) * DLAT;
            #pragma unroll
            for (int e = 0; e < DLAT; ++e) acc[e] += vv[j] * w[e];
        }
    }
    // butterfly reduce across the 64-lane wave (all lanes end with the full sum)
    #pragma unroll
    for (int e = 0; e < DLAT; ++e) {
        float a = acc[e];
        #pragma unroll
        for (int o = 32; o > 0; o >>= 1) a += __shfl_xor(a, o, 64);
        acc[e] = a;
    }

    // ---- FSQ quantize: z_q = rint(half * tanh(h))   (rint = half-to-even, like jnp.round)
    const float halfv[DLAT] = {3.f, 2.f, 2.f, 2.f, 2.f};
    float zqv[DLAT];
    int   ci[DLAT];
    #pragma unroll
    for (int e = 0; e < DLAT; ++e) {
        const float zsq = halfv[e] * tanhf(acc[e]);
        zqv[e] = rintf(zsq);
        ci[e]  = (int)zqv[e];
    }

    if (lane < DLAT) {
        ze[t * DLAT + lane] = acc[lane];
        zq[t * DLAT + lane] = zqv[lane];
    }
    if (lane == 0) {
        const int idx = ((((ci[0] + 3) * 5 + (ci[1] + 2)) * 5 + (ci[2] + 2)) * 5
                          + (ci[3] + 2)) * 5 + (ci[4] + 2);
        used[idx] = 1;   // benign race: everyone stores 1
    }

    // ---- decode: x_out[t,d] = sum_e z_q[e] * Wdec[e,d]
    #pragma unroll
    for (int q = 0; q < 4; ++q) {
        const int c0 = q * 256 + lane * 4;
        float4 o;
        float* op = (float*)&o;
        #pragma unroll
        for (int j = 0; j < 4; ++j) {
            const int d = c0 + j;
            float sum = 0.f;
            #pragma unroll
            for (int e = 0; e < DLAT; ++e) sum += zqv[e] * Wdec[e * DIM + d];
            op[j] = sum;
        }
        *(float4*)(xout + row + c0) = o;
    }
}

// ---------------------------------------------------------------------------
// K2: reduce usage flags -> unique; write the three scalar outputs.
__global__ void finalize(const int* __restrict__ used, float* __restrict__ scal) {
    __shared__ int sh[256];
    const int t = threadIdx.x;
    int sum = 0;
    for (int i = t; i < K_CB; i += 256) sum += used[i];
    sh[t] = sum;
    __syncthreads();
    for (int o = 128; o > 0; o >>= 1) {
        if (t < o) sh[t] += sh[t + o];
        __syncthreads();
    }
    if (t == 0) {
        const float uniq  = (float)sh[0];
        const float usage = (uniq + ((float)K_CB - uniq) * expf(-1.0f)) / (float)K_CB;
        scal[0] = usage;          // output 3: usage
        scal[1] = uniq;           // output 4: unique (int32 value, stored as float)
        scal[2] = 0.0f;           // output 5: percent_masked
    }
}

// ---------------------------------------------------------------------------
extern "C" void kernel_launch(void* const* d_in, const int* in_sizes, int n_in,
                              void* d_out, int out_size, void* d_ws, size_t ws_size,
                              hipStream_t stream) {
    const float* x    = (const float*)d_in[0];   // [16,2048,1024]
    const float* Wenc = (const float*)d_in[1];   // [1024,5]
    const float* Wdec = (const float*)d_in[2];   // [5,1024]

    float* out  = (float*)d_out;
    float* xout = out;                                  // 33554432
    float* ze   = out + 33554432;                       // 163840
    float* zq   = ze + 163840;                          // 163840
    float* scal = zq + 163840;                          // 3 scalars

    int* used = (int*)d_ws;                             // 4375 ints

    init_used<<<(K_CB + 255) / 256, 256, 0, stream>>>(used);
    fsq_fused<<<(32768 / 4), 256, 0, stream>>>(x, Wenc, Wdec, xout, ze, zq, used);
    finalize<<<1, 256, 0, stream>>>(used, scal);
}

// Round 3
// 52.838 us; speedup vs baseline: 2.1195x; 1.2185x over previous
//
#include <hip/hip_runtime.h>

#define MAX_SEQ   2048
#define LAT_SEQ   1024
#define DIM       1024
#define DLAT      5
#define K_CB      4375
#define ZERO_IDX  2187   // (0+3)*625 + (0+2)*125 + (0+2)*25 + (0+2)*5 + (0+2)

// ---------------------------------------------------------------------------
// K0: init usage bitmap (+ the always-used all-zero code) and build
// WencT[5][1024] so encode reads are float4-coalesced.
__global__ void prep(const float* __restrict__ Wenc,
                     float* __restrict__ WencT,
                     int* __restrict__ used) {
    int i = blockIdx.x * blockDim.x + threadIdx.x;      // 0..5119
    if (i < 5120) {
        int e = i >> 10, d = i & 1023;
        WencT[i] = Wenc[d * DLAT + e];
    }
    if (i < K_CB) used[i] = (i == ZERO_IDX) ? 1 : 0;
}

// ---------------------------------------------------------------------------
// K1: encode + FSQ quantize + usage mark. One wave per token.
__global__ __launch_bounds__(256) void fsq_enc(
    const float* __restrict__ x,
    const float* __restrict__ WencT,  // [5][1024]
    float* __restrict__ ze,           // [32768][5]
    float* __restrict__ zq,           // [32768][5]
    int*   __restrict__ used)         // [4375]
{
    const int wave = threadIdx.x >> 6;
    const int lane = threadIdx.x & 63;
    const int t    = blockIdx.x * 4 + wave;
    const int s    = t & (MAX_SEQ - 1);

    if (s >= LAT_SEQ) {
        if (lane < DLAT) {
            ze[t * DLAT + lane] = 0.f;
            zq[t * DLAT + lane] = 0.f;
        }
        return;
    }

    const long long row = (long long)t * DIM;
    float acc[DLAT] = {0.f, 0.f, 0.f, 0.f, 0.f};
    #pragma unroll
    for (int q = 0; q < 4; ++q) {
        const int c0 = q * 256 + lane * 4;
        const float4 v = *(const float4*)(x + row + c0);
        #pragma unroll
        for (int e = 0; e < DLAT; ++e) {
            const float4 w = *(const float4*)(WencT + e * DIM + c0);
            acc[e] += v.x * w.x + v.y * w.y + v.z * w.z + v.w * w.w;
        }
    }
    // butterfly reduce across the 64-lane wave
    #pragma unroll
    for (int e = 0; e < DLAT; ++e) {
        float a = acc[e];
        #pragma unroll
        for (int o = 32; o > 0; o >>= 1) a += __shfl_xor(a, o, 64);
        acc[e] = a;
    }

    // z_q = rint(half * tanh(h))  (rint = half-to-even, like jnp.round)
    const float halfv[DLAT] = {3.f, 2.f, 2.f, 2.f, 2.f};
    float zqv[DLAT];
    int   ci[DLAT];
    #pragma unroll
    for (int e = 0; e < DLAT; ++e) {
        const float zsq = halfv[e] * tanhf(acc[e]);
        zqv[e] = rintf(zsq);
        ci[e]  = (int)zqv[e];
    }

    if (lane < DLAT) {
        ze[t * DLAT + lane] = acc[lane];
        zq[t * DLAT + lane] = zqv[lane];
    }
    if (lane == 0) {
        const int idx = ((((ci[0] + 3) * 5 + (ci[1] + 2)) * 5 + (ci[2] + 2)) * 5
                          + (ci[3] + 2)) * 5 + (ci[4] + 2);
        used[idx] = 1;   // benign race: everyone stores 1
    }
}

// ---------------------------------------------------------------------------
// K2: decode write-stream. One wave per token row; masked rows are pure
// zero-stores with no loads and no dependency chain.
__global__ __launch_bounds__(256) void fsq_dec(
    const float* __restrict__ Wdec,   // [5][1024]
    const float* __restrict__ zq,     // [32768][5]
    float* __restrict__ xout)         // [32768][1024]
{
    const int wave = threadIdx.x >> 6;
    const int lane = threadIdx.x & 63;
    const int t    = blockIdx.x * 4 + wave;
    const int s    = t & (MAX_SEQ - 1);
    const long long row = (long long)t * DIM;

    if (s >= LAT_SEQ) {
        const float4 z4 = make_float4(0.f, 0.f, 0.f, 0.f);
        #pragma unroll
        for (int q = 0; q < 4; ++q)
            *(float4*)(xout + row + q * 256 + lane * 4) = z4;
        return;
    }

    float z[DLAT];
    #pragma unroll
    for (int e = 0; e < DLAT; ++e) z[e] = zq[t * DLAT + e];   // wave-uniform

    #pragma unroll
    for (int q = 0; q < 4; ++q) {
        const int c0 = q * 256 + lane * 4;
        float4 o = make_float4(0.f, 0.f, 0.f, 0.f);
        #pragma unroll
        for (int e = 0; e < DLAT; ++e) {
            const float4 w = *(const float4*)(Wdec + e * DIM + c0);
            o.x += z[e] * w.x; o.y += z[e] * w.y;
            o.z += z[e] * w.z; o.w += z[e] * w.w;
        }
        *(float4*)(xout + row + c0) = o;
    }
}

// ---------------------------------------------------------------------------
// K3: reduce usage flags -> unique; write the three scalar outputs.
__global__ void finalize(const int* __restrict__ used, float* __restrict__ scal) {
    __shared__ int sh[256];
    const int t = threadIdx.x;
    int sum = 0;
    for (int i = t; i < K_CB; i += 256) sum += used[i];
    sh[t] = sum;
    __syncthreads();
    for (int o = 128; o > 0; o >>= 1) {
        if (t < o) sh[t] += sh[t + o];
        __syncthreads();
    }
    if (t == 0) {
        const float uniq  = (float)sh[0];
        const float usage = (uniq + ((float)K_CB - uniq) * expf(-1.0f)) / (float)K_CB;
        scal[0] = usage;          // output 3: usage
        scal[1] = uniq;           // output 4: unique (int32 value, stored as float)
        scal[2] = 0.0f;           // output 5: percent_masked
    }
}

// ---------------------------------------------------------------------------
extern "C" void kernel_launch(void* const* d_in, const int* in_sizes, int n_in,
                              void* d_out, int out_size, void* d_ws, size_t ws_size,
                              hipStream_t stream) {
    const float* x    = (const float*)d_in[0];   // [16,2048,1024]
    const float* Wenc = (const float*)d_in[1];   // [1024,5]
    const float* Wdec = (const float*)d_in[2];   // [5,1024]

    float* out  = (float*)d_out;
    float* xout = out;                                  // 33554432
    float* ze   = out + 33554432;                       // 163840
    float* zq   = ze + 163840;                          // 163840
    float* scal = zq + 163840;                          // 3 scalars

    int*   used  = (int*)d_ws;                          // 4375 ints
    float* WencT = (float*)d_ws + 8192;                 // [5][1024], 20 KB

    prep<<<20, 256, 0, stream>>>(Wenc, WencT, used);
    fsq_enc<<<(32768 / 4), 256, 0, stream>>>(x, WencT, ze, zq, used);
    fsq_dec<<<(32768 / 4), 256, 0, stream>>>(Wdec, zq, xout);
    finalize<<<1, 256, 0, stream>>>(used, scal);
}